// Round 10
// baseline (118.519 us; speedup 1.0000x reference)
//
#include <hip/hip_runtime.h>

typedef __attribute__((ext_vector_type(8))) short short8;
typedef __attribute__((ext_vector_type(4))) float f32x4;

#define ROWS 16384   // B*N
#define DIM 64
#define NCODES 8192
#define MARGIN 0.008f
#define KT_FB 256
#define CTS_PER_BLOCK 32   // 512 codes per y-block

// ws layout (bytes)
#define WS_BEST   0            // 16384 * 8
#define WS_COUNTS 131072       // 8192 * 4
#define WS_ENH    163840       // 8192 * 4
#define WS_ESWZ   196608       // 8192*64*2 terms * 2B = 2097152
#define WS_NEED   2293760

__device__ __forceinline__ unsigned long long pack_score(float s, int idx) {
  unsigned u = __float_as_uint(s);
  u ^= (unsigned)((int)u >> 31) | 0x80000000u;
  return ((unsigned long long)u << 32) | (unsigned)(0xFFFF - idx);
}
__device__ __forceinline__ unsigned short bf16hi(float f) {
  unsigned u = __float_as_uint(f);
  return (unsigned short)((u + 0x7FFFu + ((u >> 16) & 1u)) >> 16);
}

__global__ void vq_enorm(const float* __restrict__ embed, float* __restrict__ enh) {
  int k = blockIdx.x * 256 + threadIdx.x;
  const float4* e4 = (const float4*)(embed + (size_t)k * DIM);
  float a = 0.f, b = 0.f, c = 0.f, d = 0.f;
#pragma unroll
  for (int i = 0; i < DIM / 4; ++i) {
    float4 v = e4[i];
    a = fmaf(v.x, v.x, a); b = fmaf(v.y, v.y, b);
    c = fmaf(v.z, v.z, c); d = fmaf(v.w, v.w, d);
  }
  enh[k] = 0.5f * ((a + b) + (c + d));
}

// Pre-swizzle embed into MFMA B-fragment order, split hi/lo bf16.
// frag index = ct*4 + kc*2 + term (term 0=hi, 1=lo); element l*16B within frag.
__global__ void vq_prep_e(const float* __restrict__ embed, short* __restrict__ eswz) {
  int u = blockIdx.x * 256 + threadIdx.x;  // 65536 = 512ct * 2kc * 64l
  int l = u & 63, kc = (u >> 6) & 1, ct = u >> 7;
  int code = ct * 16 + (l & 15);
  int kb = kc * 32 + (l >> 4) * 8;
  const float* er = embed + (size_t)code * DIM + kb;
  short8 h8, l8;
#pragma unroll
  for (int j = 0; j < 8; ++j) {
    float v = er[j];
    unsigned short h = bf16hi(v);
    float r = v - __uint_as_float((unsigned)h << 16);
    h8[j] = (short)h;
    l8[j] = (short)bf16hi(r);
  }
  short8* dst = (short8*)eswz;
  size_t frag = (size_t)ct * 4 + kc * 2;
  dst[(frag + 0) * 64 + l] = h8;
  dst[(frag + 1) * 64 + l] = l8;
}

// Screen: wave = 32 rows x 512 codes, NO LDS, NO barriers. r5/r6/r9 all hit
// the same ~95 us wall (MfmaUtil 22) regardless of staging scheme: the B-frag
// load was always issued at the head of each ct and consumed immediately ->
// full load latency on every ct's critical path (compiler never pipelines it).
// Fix: explicit distance-1 REGISTER prefetch - load ct+1's fragments into
// named regs before computing ct, rotate at compile time (fully unrolled).
// 4 independent 3-deep MFMA chains (k-split), prefetched eh folded into the
// k0 init. Float top-1 compare, margin-gated exact fp32 rescore, packed u64
// atomicMax (bit-exact vs numpy argmax). ~110 VGPR: inside the 4-wave tier.
__global__ __launch_bounds__(256, 4) void vq_screen(
    const float* __restrict__ x, const float* __restrict__ embed,
    const short* __restrict__ eswz, const float* __restrict__ enh,
    unsigned long long* __restrict__ best) {
  const int t = threadIdx.x;
  const int l = t & 63, wid = t >> 6;
  const int cl = l & 15, grp = l >> 4;
  const int row0 = blockIdx.x * 128 + wid * 32;
  const int ct0 = blockIdx.y * CTS_PER_BLOCK;

  // A fragments: x rows -> hi/lo bf16, built in-register (one-time).
  short8 ahi[2][2], alo[2][2];
#pragma unroll
  for (int s = 0; s < 2; ++s) {
    const float4* xr4 = (const float4*)(x + (size_t)(row0 + s * 16 + cl) * DIM);
#pragma unroll
    for (int kc = 0; kc < 2; ++kc) {
      const int q = kc * 8 + grp * 2;  // float4 index of kb = kc*32+grp*8
      float4 v0 = xr4[q], v1 = xr4[q + 1];
      float vv[8] = {v0.x, v0.y, v0.z, v0.w, v1.x, v1.y, v1.z, v1.w};
#pragma unroll
      for (int j = 0; j < 8; ++j) {
        unsigned short h = bf16hi(vv[j]);
        float r = vv[j] - __uint_as_float((unsigned)h << 16);
        ahi[s][kc][j] = (short)h;
        alo[s][kc][j] = (short)bf16hi(r);
      }
    }
  }

  float bsc[2][4];
  int bidx[2][4];
#pragma unroll
  for (int s = 0; s < 2; ++s)
#pragma unroll
    for (int j = 0; j < 4; ++j) { bsc[s][j] = -3.4e38f; bidx[s][j] = 0; }

  const short8* eb = (const short8*)eswz + (size_t)ct0 * 4 * 64;

  // prologue: ct0's fragments + enh into current regs
  short8 h0 = eb[l], l0 = eb[64 + l], h1 = eb[128 + l], l1 = eb[192 + l];
  float eh = enh[ct0 * 16 + cl];

#pragma unroll
  for (int ci = 0; ci < CTS_PER_BLOCK; ++ci) {
    // issue ct+1's loads BEFORE computing ct: latency hides under the MFMAs
    short8 nh0, nl0, nh1, nl1;
    float neh;
    if (ci + 1 < CTS_PER_BLOCK) {
      const short8* nb = eb + (size_t)(ci + 1) * 256;
      nh0 = nb[l]; nl0 = nb[64 + l]; nh1 = nb[128 + l]; nl1 = nb[192 + l];
      neh = enh[(ct0 + ci + 1) * 16 + cl];
    }

    f32x4 a00 = {-eh, -eh, -eh, -eh};  // slot0, k-chunk0 (carries the bias; eh prefetched)
    f32x4 a10 = a00;                   // slot1, k-chunk0
    f32x4 a01 = {0.f, 0.f, 0.f, 0.f};  // slot0, k-chunk1
    f32x4 a11 = a01;                   // slot1, k-chunk1
    // 4 independent chains, 3 MFMAs deep, interleaved round-robin
    a00 = __builtin_amdgcn_mfma_f32_16x16x32_bf16(ahi[0][0], h0, a00, 0, 0, 0);
    a10 = __builtin_amdgcn_mfma_f32_16x16x32_bf16(ahi[1][0], h0, a10, 0, 0, 0);
    a01 = __builtin_amdgcn_mfma_f32_16x16x32_bf16(ahi[0][1], h1, a01, 0, 0, 0);
    a11 = __builtin_amdgcn_mfma_f32_16x16x32_bf16(ahi[1][1], h1, a11, 0, 0, 0);
    a00 = __builtin_amdgcn_mfma_f32_16x16x32_bf16(alo[0][0], h0, a00, 0, 0, 0);
    a10 = __builtin_amdgcn_mfma_f32_16x16x32_bf16(alo[1][0], h0, a10, 0, 0, 0);
    a01 = __builtin_amdgcn_mfma_f32_16x16x32_bf16(alo[0][1], h1, a01, 0, 0, 0);
    a11 = __builtin_amdgcn_mfma_f32_16x16x32_bf16(alo[1][1], h1, a11, 0, 0, 0);
    a00 = __builtin_amdgcn_mfma_f32_16x16x32_bf16(ahi[0][0], l0, a00, 0, 0, 0);
    a10 = __builtin_amdgcn_mfma_f32_16x16x32_bf16(ahi[1][0], l0, a10, 0, 0, 0);
    a01 = __builtin_amdgcn_mfma_f32_16x16x32_bf16(ahi[0][1], l1, a01, 0, 0, 0);
    a11 = __builtin_amdgcn_mfma_f32_16x16x32_bf16(ahi[1][1], l1, a11, 0, 0, 0);

    f32x4 s0 = a00 + a01;  // merge k-chunks
    f32x4 s1 = a10 + a11;
    const int code = (ct0 + ci) * 16 + cl;
#pragma unroll
    for (int j = 0; j < 4; ++j) {
      if (s0[j] > bsc[0][j]) { bsc[0][j] = s0[j]; bidx[0][j] = code; }
      if (s1[j] > bsc[1][j]) { bsc[1][j] = s1[j]; bidx[1][j] = code; }
    }

    if (ci + 1 < CTS_PER_BLOCK) {  // compile-time rotate
      h0 = nh0; l0 = nl0; h1 = nh1; l1 = nl1; eh = neh;
    }
  }

  // Row max over the 16 lanes (l&15) of each group; flag lane-bests within margin.
  unsigned fmask = 0;
#pragma unroll
  for (int s = 0; s < 2; ++s)
#pragma unroll
    for (int j = 0; j < 4; ++j) {
      float m = bsc[s][j];
      m = fmaxf(m, __shfl_xor(m, 1));
      m = fmaxf(m, __shfl_xor(m, 2));
      m = fmaxf(m, __shfl_xor(m, 4));
      m = fmaxf(m, __shfl_xor(m, 8));
      if (bsc[s][j] >= m - MARGIN) fmask |= 1u << (s * 4 + j);
    }

  // Exact fp32 rescore of flagged candidates (typically 1/lane), lane-compacted.
  float exact[2][4];
#pragma unroll
  for (int s = 0; s < 2; ++s)
#pragma unroll
    for (int j = 0; j < 4; ++j) exact[s][j] = -3.4e38f;

  while (__any((int)(fmask != 0))) {
    const bool act = fmask != 0;
    const int sel = act ? __ffs(fmask) - 1 : 0;
    int code = 0;
#pragma unroll
    for (int s = 0; s < 2; ++s)
#pragma unroll
      for (int j = 0; j < 4; ++j)
        code = (sel == s * 4 + j) ? bidx[s][j] : code;
    int row = act ? (row0 + (sel >> 2) * 16 + grp * 4 + (sel & 3)) : row0;
    if (!act) code = 0;
    const float4* xr = (const float4*)(x + (size_t)row * DIM);
    const float4* er = (const float4*)(embed + (size_t)code * DIM);
    float a0 = 0, a1 = 0, a2 = 0, a3 = 0, n0 = 0, n1 = 0, n2 = 0, n3 = 0;
#pragma unroll
    for (int i = 0; i < 16; ++i) {
      float4 xv = xr[i], ev = er[i];
      a0 = fmaf(xv.x, ev.x, a0); a1 = fmaf(xv.y, ev.y, a1);
      a2 = fmaf(xv.z, ev.z, a2); a3 = fmaf(xv.w, ev.w, a3);
      n0 = fmaf(ev.x, ev.x, n0); n1 = fmaf(ev.y, ev.y, n1);
      n2 = fmaf(ev.z, ev.z, n2); n3 = fmaf(ev.w, ev.w, n3);
    }
    float ex = ((a0 + a1) + (a2 + a3)) - 0.5f * ((n0 + n1) + (n2 + n3));
#pragma unroll
    for (int s = 0; s < 2; ++s)
#pragma unroll
      for (int j = 0; j < 4; ++j)
        exact[s][j] = (act && sel == s * 4 + j) ? ex : exact[s][j];
    fmask = act ? (fmask & (fmask - 1)) : 0u;
  }

  // (exact score, lowest-idx) reduce across the 16-lane group; atomicMax combine.
#pragma unroll
  for (int s = 0; s < 2; ++s)
#pragma unroll
    for (int j = 0; j < 4; ++j) {
      unsigned long long pk = pack_score(exact[s][j], bidx[s][j]);
      unsigned long long o;
      o = __shfl_xor(pk, 1); pk = pk > o ? pk : o;
      o = __shfl_xor(pk, 2); pk = pk > o ? pk : o;
      o = __shfl_xor(pk, 4); pk = pk > o ? pk : o;
      o = __shfl_xor(pk, 8); pk = pk > o ? pk : o;
      if (cl == 0) atomicMax(&best[row0 + s * 16 + grp * 4 + j], pk);
    }
}

// Fallback (proven round-1 path) if ws is too small for the MFMA screen.
__global__ __launch_bounds__(256, 2) void vq_score_fb(
    const float* __restrict__ x, const float* __restrict__ embed,
    const float* __restrict__ enh, unsigned long long* __restrict__ best) {
  const int row = blockIdx.x * 256 + threadIdx.x;
  const int c0 = blockIdx.y * KT_FB;
  float4 xa[16];
  const float4* xg = (const float4*)(x + (size_t)row * DIM);
#pragma unroll
  for (int i = 0; i < 16; ++i) xa[i] = xg[i];
  float bs = -3.4e38f;
  int bc = 0;
#pragma unroll 2
  for (int c = c0; c < c0 + KT_FB; ++c) {
    const float4* e4 = (const float4*)(embed + (size_t)c * DIM);
    float a0 = 0.f, a1 = 0.f, a2 = 0.f, a3 = 0.f;
#pragma unroll
    for (int i = 0; i < 16; ++i) {
      float4 ev = e4[i];
      a0 = fmaf(xa[i].x, ev.x, a0); a1 = fmaf(xa[i].y, ev.y, a1);
      a2 = fmaf(xa[i].z, ev.z, a2); a3 = fmaf(xa[i].w, ev.w, a3);
    }
    float s = ((a0 + a1) + (a2 + a3)) - enh[c];
    if (s > bs) { bs = s; bc = c; }
  }
  atomicMax(&best[row], pack_score(bs, bc));
}

__global__ void vq_finalize(const unsigned long long* __restrict__ best,
                            const float* __restrict__ embed,
                            const float* __restrict__ node_mask,
                            float* __restrict__ quant,
                            float* __restrict__ out_idx,
                            float* __restrict__ counts) {
  int gid = blockIdx.x * 256 + threadIdx.x;
  int row = gid >> 6, d = gid & 63;
  unsigned long long p = best[row];
  int idx = 0xFFFF - (int)(p & 0xFFFFull);
  quant[gid] = embed[(size_t)idx * DIM + d];
  if (d == 0) {
    out_idx[row] = (float)idx;
    atomicAdd(&counts[idx], node_mask[row]);
  }
}

__global__ void vq_perplexity(const float* __restrict__ counts, float* __restrict__ out) {
  int tid = threadIdx.x;
  float acc = 0.f;
  for (int k = tid; k < NCODES; k += 256) {
    float p = counts[k] * (1.0f / (float)ROWS);
    acc += p * logf(p + 1e-10f);
  }
#pragma unroll
  for (int off = 32; off > 0; off >>= 1) acc += __shfl_down(acc, off);
  __shared__ float red[4];
  if ((tid & 63) == 0) red[tid >> 6] = acc;
  __syncthreads();
  if (tid == 0) out[0] = expf(-((red[0] + red[1]) + (red[2] + red[3])));
}

extern "C" void kernel_launch(void* const* d_in, const int* in_sizes, int n_in,
                              void* d_out, int out_size, void* d_ws, size_t ws_size,
                              hipStream_t stream) {
  const float* x = (const float*)d_in[0];
  const float* node_mask = (const float*)d_in[1];
  const float* embed = (const float*)d_in[2];

  float* out = (float*)d_out;
  float* quant = out;
  float* out_idx = out + (size_t)ROWS * DIM;
  float* out_ppl = out_idx + ROWS;

  unsigned long long* best = (unsigned long long*)((char*)d_ws + WS_BEST);
  float* counts = (float*)((char*)d_ws + WS_COUNTS);
  float* enh = (float*)((char*)d_ws + WS_ENH);
  short* eswz = (short*)((char*)d_ws + WS_ESWZ);

  hipMemsetAsync(d_ws, 0, WS_ENH, stream);  // best + counts
  vq_enorm<<<NCODES / 256, 256, 0, stream>>>(embed, enh);
  if (ws_size >= WS_NEED) {
    vq_prep_e<<<256, 256, 0, stream>>>(embed, eswz);
    vq_screen<<<dim3(ROWS / 128, NCODES / (CTS_PER_BLOCK * 16)), 256, 0, stream>>>(
        x, embed, eswz, enh, best);
  } else {
    vq_score_fb<<<dim3(ROWS / 256, NCODES / KT_FB), 256, 0, stream>>>(x, embed, enh, best);
  }
  vq_finalize<<<ROWS * DIM / 256, 256, 0, stream>>>(best, embed, node_mask, quant, out_idx, counts);
  vq_perplexity<<<1, 256, 0, stream>>>(counts, out_ppl);
}